// Round 5
// baseline (1637.282 us; speedup 1.0000x reference)
//
#include <hip/hip_runtime.h>
#include <hip/hip_bf16.h>
#include <math.h>

// Problem dims (fixed)
#define BB 2
#define LL 1024
#define DM 768
#define NL 8
#define DS 16
#define DC 4
#define DI 1536
#define DTR 48
#define NTOK (BB*LL)          // 2048
#define WXROWS (DTR + 2*DS)   // 80
#define NC 32                 // scan chunks
#define CT (LL/NC)            // 32 timesteps per chunk
#define SKS 8                 // split-K for W_x GEMM
#define SKC (DI/SKS)          // 192 per split
#define SK4 3                 // split-K for W_out GEMM
#define SK4C (DI/SK4)         // 512 per split

typedef __attribute__((ext_vector_type(8))) short bf16x8;
typedef __attribute__((ext_vector_type(4))) float f32x4;

__device__ inline void gload_lds16(const void* g, void* l) {
    __builtin_amdgcn_global_load_lds(
        (const __attribute__((address_space(1))) unsigned int*)g,
        (__attribute__((address_space(3))) unsigned int*)l, 16, 0, 0);
}

// bijective XCD swizzle for nwg % 8 == 0: each XCD gets a contiguous chunk
__device__ inline int xcd_swz(int orig, int nwg) {
    return (orig & 7) * (nwg >> 3) + (orig >> 3);
}

// ---------------- transpose input: batch[b,d,l] -> h[b,l,d] ----------------
__global__ __launch_bounds__(256) void transpose_in_kernel(
    const float* __restrict__ batch, float* __restrict__ h)
{
    int idx = blockIdx.x * 256 + threadIdx.x;
    if (idx >= BB*LL*DM) return;
    int d = idx % DM;
    int l = (idx / DM) % LL;
    int b = idx / (DM * LL);
    h[idx] = batch[((size_t)b*DM + d)*LL + l];
}

// ---------------- lengths from mask (robust to bool vs int32) ----------------
__global__ void lengths_kernel(const void* __restrict__ mask, int* __restrict__ lengths)
{
    int b = threadIdx.x;
    if (b >= BB) return;
    const unsigned int* mi = (const unsigned int*)mask;
    bool packed = (mi[0] == 0x01010101u);
    int cnt = 0;
    if (packed) {
        const unsigned char* mb = (const unsigned char*)mask;
        for (int i = 0; i < LL; ++i) cnt += (mb[(size_t)b*LL + i] != 0);
    } else {
        for (int i = 0; i < LL; ++i) cnt += (mi[(size_t)b*LL + i] != 0);
    }
    lengths[b] = cnt;
}

// ---------------- f32 -> bf16 conversion (4 elems/thread) ----------------
__global__ __launch_bounds__(256) void cvt_bf16_kernel(
    const float* __restrict__ in, __hip_bfloat16* __restrict__ o, int n)
{
    int i = (blockIdx.x * 256 + threadIdx.x) * 4;
    if (i >= n) return;
    float4 v = *(const float4*)(in + i);
    __hip_bfloat16 h0 = __float2bfloat16(v.x);
    __hip_bfloat16 h1 = __float2bfloat16(v.y);
    __hip_bfloat16 h2 = __float2bfloat16(v.z);
    __hip_bfloat16 h3 = __float2bfloat16(v.w);
    ushort4 r;
    r.x = *(unsigned short*)&h0; r.y = *(unsigned short*)&h1;
    r.z = *(unsigned short*)&h2; r.w = *(unsigned short*)&h3;
    *(ushort4*)(o + i) = r;
}

// f32 -> bf16 with zero-padding beyond n_src
__global__ __launch_bounds__(256) void cvt_pad_bf16_kernel(
    const float* __restrict__ in, __hip_bfloat16* __restrict__ o,
    int n_src, int n_tot)
{
    int i = (blockIdx.x * 256 + threadIdx.x) * 4;
    if (i >= n_tot) return;
    ushort4 r = {0, 0, 0, 0};
    if (i + 3 < n_src) {
        float4 v = *(const float4*)(in + i);
        __hip_bfloat16 h0 = __float2bfloat16(v.x);
        __hip_bfloat16 h1 = __float2bfloat16(v.y);
        __hip_bfloat16 h2 = __float2bfloat16(v.z);
        __hip_bfloat16 h3 = __float2bfloat16(v.w);
        r.x = *(unsigned short*)&h0; r.y = *(unsigned short*)&h1;
        r.z = *(unsigned short*)&h2; r.w = *(unsigned short*)&h3;
    }
    *(ushort4*)(o + i) = r;
}

// ---------------- RMSNorm (per token, D=768) -> bf16 out ----------------
__global__ __launch_bounds__(256) void rmsnorm_kernel(
    const float* __restrict__ x, const float* __restrict__ w,
    __hip_bfloat16* __restrict__ o)
{
    int tok = blockIdx.x;
    const float* xr = x + (size_t)tok * DM;
    float ss = 0.f;
    for (int j = threadIdx.x; j < DM; j += 256) { float v = xr[j]; ss += v*v; }
    #pragma unroll
    for (int off = 32; off > 0; off >>= 1) ss += __shfl_down(ss, off);
    __shared__ float red[4];
    int lane = threadIdx.x & 63, wv = threadIdx.x >> 6;
    if (lane == 0) red[wv] = ss;
    __syncthreads();
    if (threadIdx.x == 0) {
        float t = red[0] + red[1] + red[2] + red[3];
        red[0] = rsqrtf(t / (float)DM + 1e-5f);
    }
    __syncthreads();
    float r = red[0];
    for (int j = threadIdx.x; j < DM; j += 256)
        o[(size_t)tok*DM + j] = __float2bfloat16(xr[j] * w[j] * r);
}

// ---------------- MFMA bf16 GEMM (full K, 1D swizzled grid): C = A @ W^T ----------------
// A:[M,K] bf16, W:[N,K] bf16, C bf16 (BF16OUT=1) or f32. NT = N/128 tiles.
template<int BF16OUT>
__global__ __launch_bounds__(256) void gemm_mfma_kernel(
    const __hip_bfloat16* __restrict__ A,
    const __hip_bfloat16* __restrict__ W,
    void* __restrict__ Cv,
    int NT, int M, int N, int K)
{
    __shared__ short As[128*32];
    __shared__ short Ws[128*32];
    const int swz = xcd_swz(blockIdx.x, gridDim.x);
    const int bn = (swz % NT) * 128;
    const int bm = (swz / NT) * 128;
    const int t = threadIdx.x;
    const int w = t >> 6;
    const int lane = t & 63;
    const int wr = w >> 1, wc = w & 1;
    const int fr = lane & 15;
    const int khi = lane >> 4;

    f32x4 acc[4][4];
    #pragma unroll
    for (int mi = 0; mi < 4; ++mi)
        #pragma unroll
        for (int ni = 0; ni < 4; ++ni)
            acc[mi][ni] = (f32x4){0.f, 0.f, 0.f, 0.f};

    const int rowL = t >> 2;
    const int ks = (t & 3) * 8;
    const __hip_bfloat16* gA0 = A + (size_t)(bm + rowL) * K + ks;
    const __hip_bfloat16* gA1 = A + (size_t)(bm + 64 + rowL) * K + ks;
    const __hip_bfloat16* gW0 = W + (size_t)(bn + rowL) * K + ks;
    const __hip_bfloat16* gW1 = W + (size_t)(bn + 64 + rowL) * K + ks;
    short* AsW = As + w * 512;
    short* WsW = Ws + w * 512;

    for (int k0 = 0; k0 < K; k0 += 32) {
        gload_lds16(gA0 + k0, AsW);
        gload_lds16(gA1 + k0, AsW + 2048);
        gload_lds16(gW0 + k0, WsW);
        gload_lds16(gW1 + k0, WsW + 2048);
        asm volatile("s_waitcnt vmcnt(0)" ::: "memory");
        __syncthreads();
        bf16x8 a[4], b[4];
        #pragma unroll
        for (int mi = 0; mi < 4; ++mi)
            a[mi] = *(const bf16x8*)&As[(wr*64 + mi*16 + fr)*32 + khi*8];
        #pragma unroll
        for (int ni = 0; ni < 4; ++ni)
            b[ni] = *(const bf16x8*)&Ws[(wc*64 + ni*16 + fr)*32 + khi*8];
        #pragma unroll
        for (int mi = 0; mi < 4; ++mi)
            #pragma unroll
            for (int ni = 0; ni < 4; ++ni)
                acc[mi][ni] = __builtin_amdgcn_mfma_f32_16x16x32_bf16(
                    a[mi], b[ni], acc[mi][ni], 0, 0, 0);
        __syncthreads();
    }

    #pragma unroll
    for (int mi = 0; mi < 4; ++mi) {
        #pragma unroll
        for (int ni = 0; ni < 4; ++ni) {
            int gc = bn + wc*64 + ni*16 + fr;
            #pragma unroll
            for (int r = 0; r < 4; ++r) {
                int gr = bm + wr*64 + mi*16 + khi*4 + r;
                size_t o = (size_t)gr * N + gc;
                if (BF16OUT) ((__hip_bfloat16*)Cv)[o] = __float2bfloat16(acc[mi][ni][r]);
                else         ((float*)Cv)[o] = acc[mi][ni][r];
            }
        }
    }
}

// ---------------- W_out GEMM split-K=3, swizzled 1D grid (288 blocks) ----------------
// A: y_bf [NTOK, DI], W: Wout_bf [DM, DI], Cp: [SK4][NTOK][DM] f32 partials
__global__ __launch_bounds__(256) void gemm_mfma_splitk4(
    const __hip_bfloat16* __restrict__ A,
    const __hip_bfloat16* __restrict__ W,
    float* __restrict__ Cp)
{
    __shared__ short As[128*32];
    __shared__ short Ws[128*32];
    const int swz = xcd_swz(blockIdx.x, gridDim.x);   // 288 blocks
    const int bm = (swz / 18) * 128;                   // 16 m-tiles
    const int r18 = swz % 18;
    const int bn = (r18 % 6) * 128;                    // 6 n-tiles
    const int split = r18 / 6;                         // 3 splits
    const int t = threadIdx.x;
    const int w = t >> 6;
    const int lane = t & 63;
    const int wr = w >> 1, wc = w & 1;
    const int fr = lane & 15;
    const int khi = lane >> 4;

    f32x4 acc[4][4];
    #pragma unroll
    for (int mi = 0; mi < 4; ++mi)
        #pragma unroll
        for (int ni = 0; ni < 4; ++ni)
            acc[mi][ni] = (f32x4){0.f, 0.f, 0.f, 0.f};

    const int rowL = t >> 2;
    const int ks = (t & 3) * 8;
    const __hip_bfloat16* gA0 = A + (size_t)(bm + rowL) * DI + ks;
    const __hip_bfloat16* gA1 = A + (size_t)(bm + 64 + rowL) * DI + ks;
    const __hip_bfloat16* gW0 = W + (size_t)(bn + rowL) * DI + ks;
    const __hip_bfloat16* gW1 = W + (size_t)(bn + 64 + rowL) * DI + ks;
    short* AsW = As + w * 512;
    short* WsW = Ws + w * 512;

    const int kbeg = split * SK4C;
    for (int k0 = kbeg; k0 < kbeg + SK4C; k0 += 32) {
        gload_lds16(gA0 + k0, AsW);
        gload_lds16(gA1 + k0, AsW + 2048);
        gload_lds16(gW0 + k0, WsW);
        gload_lds16(gW1 + k0, WsW + 2048);
        asm volatile("s_waitcnt vmcnt(0)" ::: "memory");
        __syncthreads();
        bf16x8 a[4], b[4];
        #pragma unroll
        for (int mi = 0; mi < 4; ++mi)
            a[mi] = *(const bf16x8*)&As[(wr*64 + mi*16 + fr)*32 + khi*8];
        #pragma unroll
        for (int ni = 0; ni < 4; ++ni)
            b[ni] = *(const bf16x8*)&Ws[(wc*64 + ni*16 + fr)*32 + khi*8];
        #pragma unroll
        for (int mi = 0; mi < 4; ++mi)
            #pragma unroll
            for (int ni = 0; ni < 4; ++ni)
                acc[mi][ni] = __builtin_amdgcn_mfma_f32_16x16x32_bf16(
                    a[mi], b[ni], acc[mi][ni], 0, 0, 0);
        __syncthreads();
    }

    #pragma unroll
    for (int mi = 0; mi < 4; ++mi) {
        #pragma unroll
        for (int ni = 0; ni < 4; ++ni) {
            int gc = bn + wc*64 + ni*16 + fr;
            #pragma unroll
            for (int r = 0; r < 4; ++r) {
                int gr = bm + wr*64 + mi*16 + khi*4 + r;
                Cp[((size_t)split*NTOK + gr)*DM + gc] = acc[mi][ni][r];
            }
        }
    }
}

// reduce split-K partials + residual add: h += sum_p Cp[p]
__global__ __launch_bounds__(256) void reduce_add4_kernel(
    const float* __restrict__ Cp, float* __restrict__ h)
{
    int i = (blockIdx.x * 256 + threadIdx.x) * 4;   // < NTOK*DM
    float4 a = *(const float4*)(Cp + i);
    float4 b = *(const float4*)(Cp + (size_t)NTOK*DM + i);
    float4 c = *(const float4*)(Cp + 2*(size_t)NTOK*DM + i);
    float4 hh = *(const float4*)(h + i);
    hh.x += a.x + b.x + c.x;
    hh.y += a.y + b.y + c.y;
    hh.z += a.z + b.z + c.z;
    hh.w += a.w + b.w + c.w;
    *(float4*)(h + i) = hh;
}

// ---------------- skinny MFMA split-K GEMM: dblp[split][m][0..79] ----------------
__global__ __launch_bounds__(256) void gemm_mfma_skinny(
    const __hip_bfloat16* __restrict__ A,
    const __hip_bfloat16* __restrict__ W,
    float* __restrict__ Cp)
{
    __shared__ short As[128*32];
    __shared__ short Ws[128*32];
    const int split = blockIdx.x;            // 0..SKS-1
    const int bm = blockIdx.y * 128;
    const int t = threadIdx.x;
    const int w = t >> 6;
    const int lane = t & 63;
    const int wr = w >> 1, wc = w & 1;
    const int fr = lane & 15;
    const int khi = lane >> 4;

    f32x4 acc[4][4];
    #pragma unroll
    for (int mi = 0; mi < 4; ++mi)
        #pragma unroll
        for (int ni = 0; ni < 4; ++ni)
            acc[mi][ni] = (f32x4){0.f, 0.f, 0.f, 0.f};

    const int rowL = t >> 2;
    const int ks = (t & 3) * 8;
    const __hip_bfloat16* gA0 = A + (size_t)(bm + rowL) * DI + ks;
    const __hip_bfloat16* gA1 = A + (size_t)(bm + 64 + rowL) * DI + ks;
    const __hip_bfloat16* gW0 = W + (size_t)rowL * DI + ks;
    const __hip_bfloat16* gW1 = W + (size_t)(64 + rowL) * DI + ks;
    short* AsW = As + w * 512;
    short* WsW = Ws + w * 512;

    const int kbeg = split * SKC;
    for (int k0 = kbeg; k0 < kbeg + SKC; k0 += 32) {
        gload_lds16(gA0 + k0, AsW);
        gload_lds16(gA1 + k0, AsW + 2048);
        gload_lds16(gW0 + k0, WsW);
        gload_lds16(gW1 + k0, WsW + 2048);
        asm volatile("s_waitcnt vmcnt(0)" ::: "memory");
        __syncthreads();
        bf16x8 a[4], b[4];
        #pragma unroll
        for (int mi = 0; mi < 4; ++mi)
            a[mi] = *(const bf16x8*)&As[(wr*64 + mi*16 + fr)*32 + khi*8];
        #pragma unroll
        for (int ni = 0; ni < 4; ++ni)
            b[ni] = *(const bf16x8*)&Ws[(wc*64 + ni*16 + fr)*32 + khi*8];
        #pragma unroll
        for (int mi = 0; mi < 4; ++mi)
            #pragma unroll
            for (int ni = 0; ni < 4; ++ni)
                acc[mi][ni] = __builtin_amdgcn_mfma_f32_16x16x32_bf16(
                    a[mi], b[ni], acc[mi][ni], 0, 0, 0);
        __syncthreads();
    }

    #pragma unroll
    for (int mi = 0; mi < 4; ++mi) {
        #pragma unroll
        for (int ni = 0; ni < 4; ++ni) {
            int gc = wc*64 + ni*16 + fr;
            if (gc >= WXROWS) continue;
            #pragma unroll
            for (int r = 0; r < 4; ++r) {
                int gr = bm + wr*64 + mi*16 + khi*4 + r;
                Cp[((size_t)split*NTOK + gr)*WXROWS + gc] = acc[mi][ni][r];
            }
        }
    }
}

// reduce split-K partials -> dbl [NTOK,80]
__global__ __launch_bounds__(256) void reduce_dbl_kernel(
    const float* __restrict__ Cp, float* __restrict__ dbl)
{
    int i = blockIdx.x * 256 + threadIdx.x;
    float s = 0.f;
    #pragma unroll
    for (int p = 0; p < SKS; ++p) s += Cp[(size_t)p*NTOK*WXROWS + i];
    dbl[i] = s;
}

// ---------------- causal depthwise conv4 + bias + SiLU (bf16 in/out) ----------------
__global__ __launch_bounds__(256) void conv_silu_kernel(
    const __hip_bfloat16* __restrict__ xz, const float* __restrict__ cw,
    const float* __restrict__ cb, __hip_bfloat16* __restrict__ u)
{
    int idx = blockIdx.x * 256 + threadIdx.x;
    if (idx >= BB*LL*DI) return;
    int d = idx % DI;
    int l = (idx / DI) % LL;
    int b = idx / (DI * LL);
    float acc = cb[d];
    #pragma unroll
    for (int k = 0; k < 4; ++k) {
        int ls = l - 3 + k;
        if (ls >= 0)
            acc = fmaf(__bfloat162float(xz[((size_t)(b*LL + ls))*(2*DI) + d]),
                       cw[d*4 + k], acc);
    }
    u[idx] = __float2bfloat16(acc / (1.f + __expf(-acc)));
}

// ================= chunk-parallel selective scan (delta fused) =================
// delta[t,d] = softplus( dot(dbl[t,0:48], W_dt[d,:]) + b_dt[d] )
__global__ __launch_bounds__(256) void scan_phaseA(
    const __hip_bfloat16* __restrict__ u,
    const float* __restrict__ dbl,
    const float* __restrict__ W_dt, const float* __restrict__ b_dt,
    const float* __restrict__ A_log,
    float* __restrict__ Psum, float* __restrict__ Hsum)
{
    const int d = blockIdx.x * 256 + threadIdx.x;
    const int c = blockIdx.y;
    const int b = blockIdx.z;
    float wdt[DTR];
    #pragma unroll
    for (int j = 0; j < DTR; j += 4) {
        float4 v = *(const float4*)(W_dt + (size_t)d*DTR + j);
        wdt[j] = v.x; wdt[j+1] = v.y; wdt[j+2] = v.z; wdt[j+3] = v.w;
    }
    const float bdt = b_dt[d];
    float A[DS], P[DS], hl[DS];
    #pragma unroll
    for (int s = 0; s < DS; ++s) {
        A[s] = -expf(A_log[(size_t)d*DS + s]);
        P[s] = 1.f; hl[s] = 0.f;
    }
    const int t0 = c * CT;
    for (int t = t0; t < t0 + CT; ++t) {
        const size_t row = (size_t)b*LL + t;
        const float* rowp = dbl + row*WXROWS;   // uniform address -> scalar loads
        float dt = bdt;
        #pragma unroll
        for (int j = 0; j < DTR; ++j) dt = fmaf(rowp[j], wdt[j], dt);
        dt = (dt > 20.f) ? dt : log1pf(__expf(dt));
        float du = dt * __bfloat162float(u[row*DI + d]);
        const float* bc = rowp + DTR;
        #pragma unroll
        for (int s = 0; s < DS; ++s) {
            float a = __expf(dt * A[s]);
            P[s] *= a;
            hl[s] = fmaf(a, hl[s], du * bc[s]);
        }
    }
    const size_t off = (((size_t)b*NC + c)*DI + d)*DS;
    #pragma unroll
    for (int s = 0; s < DS; ++s) { Psum[off+s] = P[s]; Hsum[off+s] = hl[s]; }
}

__global__ __launch_bounds__(256) void scan_phaseB(
    const float* __restrict__ Psum, const float* __restrict__ Hsum,
    float* __restrict__ Hin)
{
    const int gid = blockIdx.x * 256 + threadIdx.x;
    if (gid >= BB*DI*DS) return;
    const int b = gid / (DI*DS);
    const int r = gid % (DI*DS);
    float hc = 0.f;
    for (int c = 0; c < NC; ++c) {
        const size_t off = ((size_t)(b*NC + c))*DI*DS + r;
        Hin[off] = hc;
        hc = fmaf(Psum[off], hc, Hsum[off]);
    }
}

// Phase C: rerun recurrence from Hin, gated output -> bf16 (delta fused)
__global__ __launch_bounds__(256) void scan_phaseC(
    const __hip_bfloat16* __restrict__ u,
    const float* __restrict__ dbl,
    const float* __restrict__ W_dt, const float* __restrict__ b_dt,
    const __hip_bfloat16* __restrict__ xz,
    const float* __restrict__ A_log, const float* __restrict__ Dsk,
    const float* __restrict__ Hin, __hip_bfloat16* __restrict__ yfull)
{
    const int d = blockIdx.x * 256 + threadIdx.x;
    const int c = blockIdx.y;
    const int b = blockIdx.z;
    float wdt[DTR];
    #pragma unroll
    for (int j = 0; j < DTR; j += 4) {
        float4 v = *(const float4*)(W_dt + (size_t)d*DTR + j);
        wdt[j] = v.x; wdt[j+1] = v.y; wdt[j+2] = v.z; wdt[j+3] = v.w;
    }
    const float bdt = b_dt[d];
    float A[DS], h[DS];
    const size_t hoff = (((size_t)b*NC + c)*DI + d)*DS;
    #pragma unroll
    for (int s = 0; s < DS; ++s) {
        A[s] = -expf(A_log[(size_t)d*DS + s]);
        h[s] = Hin[hoff + s];
    }
    const float dsk = Dsk[d];
    const int t0 = c * CT;
    for (int t = t0; t < t0 + CT; ++t) {
        const size_t row = (size_t)b*LL + t;
        const float* rowp = dbl + row*WXROWS;
        float dt = bdt;
        #pragma unroll
        for (int j = 0; j < DTR; ++j) dt = fmaf(rowp[j], wdt[j], dt);
        dt = (dt > 20.f) ? dt : log1pf(__expf(dt));
        float ut = __bfloat162float(u[row*DI + d]);
        float du = dt * ut;
        const float* bc = rowp + DTR;
        float y = 0.f;
        #pragma unroll
        for (int s = 0; s < DS; ++s) {
            float a = __expf(dt * A[s]);
            h[s] = fmaf(a, h[s], du * bc[s]);
            y = fmaf(h[s], bc[DS+s], y);
        }
        float zt = __bfloat162float(xz[row*(2*DI) + DI + d]);
        float sz = zt / (1.f + __expf(-zt));
        yfull[row*DI + d] = __float2bfloat16((y + ut * dsk) * sz);
    }
}

// ---------------- final rmsnorm + gather last valid token ----------------
__global__ __launch_bounds__(256) void final_kernel(
    const float* __restrict__ h, const float* __restrict__ w,
    const int* __restrict__ lengths, float* __restrict__ out)
{
    int b = blockIdx.x;
    int idx = lengths[b] - 1;
    const float* xr = h + ((size_t)b*LL + idx)*DM;
    float ss = 0.f;
    for (int j = threadIdx.x; j < DM; j += 256) { float v = xr[j]; ss += v*v; }
    #pragma unroll
    for (int off = 32; off > 0; off >>= 1) ss += __shfl_down(ss, off);
    __shared__ float red[4];
    int lane = threadIdx.x & 63, wv = threadIdx.x >> 6;
    if (lane == 0) red[wv] = ss;
    __syncthreads();
    if (threadIdx.x == 0) {
        float t = red[0] + red[1] + red[2] + red[3];
        red[0] = rsqrtf(t / (float)DM + 1e-5f);
    }
    __syncthreads();
    float r = red[0];
    for (int j = threadIdx.x; j < DM; j += 256)
        out[(size_t)b*DM + j] = xr[j] * w[j] * r;
}

extern "C" void kernel_launch(void* const* d_in, const int* in_sizes, int n_in,
                              void* d_out, int out_size, void* d_ws, size_t ws_size,
                              hipStream_t stream)
{
    const float* batch   = (const float*)d_in[0];
    const void*  mask    = d_in[1];
    const float* norm_w  = (const float*)d_in[2];
    const float* W_in    = (const float*)d_in[3];
    const float* conv_w  = (const float*)d_in[4];
    const float* conv_b  = (const float*)d_in[5];
    const float* W_x     = (const float*)d_in[6];
    const float* W_dt    = (const float*)d_in[7];
    const float* b_dt    = (const float*)d_in[8];
    const float* A_log   = (const float*)d_in[9];
    const float* D_skip  = (const float*)d_in[10];
    const float* W_out   = (const float*)d_in[11];
    const float* normf_w = (const float*)d_in[12];
    float* out = (float*)d_out;

    // workspace layout (f32 region, then bf16 region)
    float* ws    = (float*)d_ws;
    float* h     = ws;                          // NTOK*DM        = 1,572,864
    float* dbl   = h    + (size_t)NTOK*DM;      // NTOK*80        =   163,840
    float* Psum  = dbl  + (size_t)NTOK*WXROWS;  // BB*NC*DI*DS    = 1,572,864
    float* Hsum  = Psum + (size_t)BB*NC*DI*DS;  //                = 1,572,864
    float* Hin   = Hsum + (size_t)BB*NC*DI*DS;  //                = 1,572,864
    // aliases (lifetimes disjoint):
    float* dblp  = Psum;  // [SKS][NTOK][80] = 1,310,720 f32, dead before scanA
    float* Cp4   = Psum;  // [SK4][NTOK][DM] = 4,718,592 f32 = Psum+Hsum+Hin, used after scanC
    __hip_bfloat16* xz_bf  = (__hip_bfloat16*)(Hin + (size_t)BB*NC*DI*DS); // NTOK*2*DI
    __hip_bfloat16* xn_bf  = xz_bf + (size_t)NTOK*2*DI;   // NTOK*DM
    __hip_bfloat16* y_bf   = xn_bf + (size_t)NTOK*DM;     // NTOK*DI
    __hip_bfloat16* u_bf   = y_bf + (size_t)NTOK*DI;      // NTOK*DI
    __hip_bfloat16* Win_bf = u_bf + (size_t)NTOK*DI;      // 2*DI*DM
    __hip_bfloat16* Wout_bf= Win_bf + (size_t)2*DI*DM;    // DM*DI
    __hip_bfloat16* Wxp_bf = Wout_bf + (size_t)DM*DI;     // 128*DI
    int*   lengths = (int*)(Wxp_bf + (size_t)128*DI);

    transpose_in_kernel<<<(BB*LL*DM + 255)/256, 256, 0, stream>>>(batch, h);
    lengths_kernel<<<1, 64, 0, stream>>>(mask, lengths);

    for (int i = 0; i < NL; ++i) {
        const float* Wi   = W_in  + (size_t)i * 2*DI * DM;
        const float* cwi  = conv_w + (size_t)i * DI * DC;
        const float* cbi  = conv_b + (size_t)i * DI;
        const float* Wxi  = W_x   + (size_t)i * WXROWS * DI;
        const float* Wdti = W_dt  + (size_t)i * DI * DTR;
        const float* bdti = b_dt  + (size_t)i * DI;
        const float* Ali  = A_log + (size_t)i * DI * DS;
        const float* Dski = D_skip + (size_t)i * DI;
        const float* Woi  = W_out + (size_t)i * DM * DI;

        // weight slices -> bf16
        cvt_bf16_kernel<<<(2*DI*DM/4 + 255)/256, 256, 0, stream>>>(Wi, Win_bf, 2*DI*DM);
        cvt_bf16_kernel<<<(DM*DI/4 + 255)/256, 256, 0, stream>>>(Woi, Wout_bf, DM*DI);
        cvt_pad_bf16_kernel<<<(128*DI/4 + 255)/256, 256, 0, stream>>>(
            Wxi, Wxp_bf, WXROWS*DI, 128*DI);

        // 1) pre-norm -> bf16
        rmsnorm_kernel<<<NTOK, 256, 0, stream>>>(h, norm_w + (size_t)i*DM, xn_bf);
        // 2) xz = xn @ W_in^T  (MFMA, bf16 out, swizzled)  [2048 x 3072], K=768
        gemm_mfma_kernel<1><<<(2*DI/128)*(NTOK/128), 256, 0, stream>>>(
            xn_bf, Win_bf, xz_bf, 2*DI/128, NTOK, 2*DI, DM);
        // 3) causal conv + SiLU -> u_bf
        conv_silu_kernel<<<(BB*LL*DI + 255)/256, 256, 0, stream>>>(xz_bf, cwi, cbi, u_bf);
        // 4) dbl = u @ W_x^T  [2048 x 80] (MFMA split-K + reduce)
        gemm_mfma_skinny<<<dim3(SKS, NTOK/128), 256, 0, stream>>>(u_bf, Wxp_bf, dblp);
        reduce_dbl_kernel<<<NTOK*WXROWS/256, 256, 0, stream>>>(dblp, dbl);

        // 5+6) chunk-parallel scan with fused delta (softplus(dtp@W_dt + b_dt))
        scan_phaseA<<<dim3(DI/256, NC, BB), 256, 0, stream>>>(
            u_bf, dbl, Wdti, bdti, Ali, Psum, Hsum);
        scan_phaseB<<<(BB*DI*DS + 255)/256, 256, 0, stream>>>(Psum, Hsum, Hin);
        scan_phaseC<<<dim3(DI/256, NC, BB), 256, 0, stream>>>(
            u_bf, dbl, Wdti, bdti, xz_bf, Ali, Dski, Hin, y_bf);

        // 7) h += y @ W_out^T  (MFMA split-K=3 + fused residual reduce)
        gemm_mfma_splitk4<<<SK4*(DM/128)*(NTOK/128), 256, 0, stream>>>(
            y_bf, Wout_bf, Cp4);
        reduce_add4_kernel<<<NTOK*DM/1024, 256, 0, stream>>>(Cp4, h);
    }

    final_kernel<<<BB, 256, 0, stream>>>(h, normf_w, lengths, out);
}